// Round 1
// baseline (328.862 us; speedup 1.0000x reference)
//
#include <hip/hip_runtime.h>
#include <stdint.h>

// StandardAttention: B=16, N=1024, DIM=768, H=12, Dh=64, SCALE=0.125
// cvt(x,w_qkv,w_proj) -> gemm_qkv (q*0.125*log2e, k, V TRANSPOSED) -> flash_attn
// (S^T form, v_exp_f32 (2^x), no online max; l via MFMA-ones) -> gemm_proj(+bias).
// GEMM: 256x256 tile, BK=64, 8 waves, 8-phase counted-vmcnt schedule (T2+T3+T4+T5).

typedef unsigned short u16;
typedef __attribute__((ext_vector_type(8))) short s16x8;   // 8 x bf16 MFMA frag
typedef __attribute__((ext_vector_type(4))) float f32x4;   // MFMA accum
typedef __attribute__((ext_vector_type(4))) unsigned short u16x4;

#define SEQ 1024
#define NHEAD 12
#define HD 64

__device__ __forceinline__ u16 f2bf(float f) {
  union { float f; uint32_t u; } v; v.f = f;
  uint32_t u = v.u;
  return (u16)((u + 0x7FFFu + ((u >> 16) & 1u)) >> 16);   // RNE
}

__device__ __forceinline__ float exp2_fast(float x) {
  return __builtin_amdgcn_exp2f(x);
}

__device__ __forceinline__ uint32_t pk_bf16(float a, float b) {
#if __has_builtin(__builtin_amdgcn_cvt_pk_bf16_f32)
  typedef __attribute__((ext_vector_type(2))) __bf16 bf2;
  union { bf2 v; uint32_t u; } c;
  c.v = __builtin_amdgcn_cvt_pk_bf16_f32(a, b);
  return c.u;
#else
  union { float f; uint32_t u; } ua, ub; ua.f = a; ub.f = b;
  const uint32_t ra = ua.u + 0x8000u, rb = ub.u + 0x8000u;
  return __builtin_amdgcn_perm(ra, rb, 0x03020706u);
#endif
}

__device__ __forceinline__ void gld_lds16(const void* g, void* l) {
  __builtin_amdgcn_global_load_lds((const __attribute__((address_space(1))) void*)g,
                                   (__attribute__((address_space(3))) void*)l, 16, 0, 0);
}

// barrier WITHOUT the __syncthreads vmcnt(0) drain; compiler fence + sched pin.
__device__ __forceinline__ void phase_bar() {
  __builtin_amdgcn_sched_barrier(0);
  asm volatile("" ::: "memory");
  __builtin_amdgcn_s_barrier();
  asm volatile("" ::: "memory");
  __builtin_amdgcn_sched_barrier(0);
}

__global__ void cvt_bf16(const float* __restrict__ in, u16* __restrict__ out, int n4) {
  int i = blockIdx.x * blockDim.x + threadIdx.x;
  if (i < n4) {
    float4 f = ((const float4*)in)[i];
    u16x4 o;
    o.x = f2bf(f.x); o.y = f2bf(f.y); o.z = f2bf(f.z); o.w = f2bf(f.w);
    ((u16x4*)out)[i] = o;
  }
}

// C = A[M,768] @ B^T, B row-major [N,768]. 256x256 tile, BK=64, 8 waves (2Mx4N).
// 4 phases per K-tile (one mi-quadrant each, 16 MFMA); per-phase region staging:
//   ph1: A-half0(t+1)  ph2: A-half1(t+1)  ph3: B-half1(t+1)  ph4: B-half0(t+2)
// one s_waitcnt vmcnt(2) per K-tile (10 outstanding -> retire 8 = all of tile t+1).
// EPI=0: scatter q(*0.125*log2e)/k to [B,H,N,64], V TRANSPOSED to [B,H,64,N].
// EPI=1: +bias, fp32 out.
template <int EPI>
__global__ __launch_bounds__(512, 2)
void gemm_bt(const u16* __restrict__ A, const u16* __restrict__ B,
             u16* __restrict__ q, u16* __restrict__ k, u16* __restrict__ v,
             float* __restrict__ out, const float* __restrict__ bias) {
  __shared__ u16 As[2][256 * 64];
  __shared__ u16 Bs[2][256 * 64];
  constexpr int NTN = (EPI == 0) ? 9 : 3;     // N tiles: 2304/256 or 768/256
  constexpr int NWG = 64 * NTN;               // 576 / 192 (both % 8 == 0)
  constexpr int CPX = NWG / 8;

  const int tid = threadIdx.x;
  const int wv = tid >> 6, lane = tid & 63;
  const int quad = lane >> 4, l16 = lane & 15;
  const int bid = blockIdx.x;
  const int swz = (bid & 7) * CPX + (bid >> 3);   // bijective XCD swizzle
  const int m0 = (swz / NTN) * 256;               // intra-XCD neighbors share A panel
  const int n0 = (swz % NTN) * 256;
  const int wm = (wv >> 2) * 128, wn = (wv & 3) * 64;
  const int srow = tid >> 3, slot = tid & 7;

// stage one 128x64 region (16 KiB = 2 x 16B/thread); chunk slot = chunk ^ (row&7)
#define STAGE_A(bufi, kt, half)                                              \
  do {                                                                       \
    _Pragma("unroll")                                                        \
    for (int j = 0; j < 2; j++) {                                            \
      const int row_ = (half) * 128 + j * 64 + srow;                         \
      const int c_ = slot ^ (row_ & 7);                                      \
      gld_lds16(A + (size_t)(m0 + row_) * 768 + (kt) + c_ * 8,               \
                &As[bufi][((half) * 128 + j * 64 + wv * 8) * 64]);           \
    }                                                                        \
  } while (0)

#define STAGE_B(bufi, kt, half)                                              \
  do {                                                                       \
    _Pragma("unroll")                                                        \
    for (int j = 0; j < 2; j++) {                                            \
      const int row_ = (half) * 128 + j * 64 + srow;                         \
      const int c_ = slot ^ (row_ & 7);                                      \
      gld_lds16(B + (size_t)(n0 + row_) * 768 + (kt) + c_ * 8,               \
                &Bs[bufi][((half) * 128 + j * 64 + wv * 8) * 64]);           \
    }                                                                        \
  } while (0)

#define READ_A(qd)                                                           \
  do {                                                                       \
    _Pragma("unroll")                                                        \
    for (int i = 0; i < 2; i++) {                                            \
      const int ra_ = wm + ((qd) * 2 + i) * 16 + l16;                        \
      _Pragma("unroll")                                                      \
      for (int ks = 0; ks < 2; ks++)                                         \
        af[i][ks] = *(const s16x8*)&As[buf][ra_ * 64 + (((ks * 4 + quad) ^ (ra_ & 7)) * 8)]; \
    }                                                                        \
  } while (0)

#define READ_B()                                                             \
  do {                                                                       \
    _Pragma("unroll")                                                        \
    for (int ni = 0; ni < 4; ni++) {                                         \
      const int rb_ = wn + ni * 16 + l16;                                    \
      _Pragma("unroll")                                                      \
      for (int ks = 0; ks < 2; ks++)                                         \
        bf[ks][ni] = *(const s16x8*)&Bs[buf][rb_ * 64 + (((ks * 4 + quad) ^ (rb_ & 7)) * 8)]; \
    }                                                                        \
  } while (0)

#define MFMA_Q(qd)                                                           \
  do {                                                                       \
    __builtin_amdgcn_s_setprio(1);                                           \
    _Pragma("unroll")                                                        \
    for (int i = 0; i < 2; i++)                                              \
      _Pragma("unroll")                                                      \
      for (int ni = 0; ni < 4; ni++) {                                       \
        acc[(qd) * 2 + i][ni] = __builtin_amdgcn_mfma_f32_16x16x32_bf16(     \
            af[i][0], bf[0][ni], acc[(qd) * 2 + i][ni], 0, 0, 0);            \
        acc[(qd) * 2 + i][ni] = __builtin_amdgcn_mfma_f32_16x16x32_bf16(     \
            af[i][1], bf[1][ni], acc[(qd) * 2 + i][ni], 0, 0, 0);            \
      }                                                                      \
    __builtin_amdgcn_s_setprio(0);                                           \
  } while (0)

  f32x4 acc[8][4];
#pragma unroll
  for (int i = 0; i < 8; i++)
#pragma unroll
    for (int j = 0; j < 4; j++) { acc[i][j].x = 0.f; acc[i][j].y = 0.f; acc[i][j].z = 0.f; acc[i][j].w = 0.f; }

  // Prologue: all of tile 0 + B-half0 of tile 1 (10 loads; retire 8 = tile 0)
  STAGE_A(0, 0, 0); STAGE_A(0, 0, 1);
  STAGE_B(0, 0, 0); STAGE_B(0, 0, 1);
  STAGE_B(1, 64, 0);
  asm volatile("s_waitcnt vmcnt(2)" ::: "memory");
  phase_bar();

  for (int t = 0; t < 12; t++) {
    const int buf = t & 1;
    const int ktn = (t + 1) * 64;
    s16x8 af[2][2], bf[2][4];

    // ---- phase 1: all B frags + A quadrant 0; stage A-half0(t+1)
    READ_B();
    READ_A(0);
    if (t < 11) STAGE_A(buf ^ 1, ktn, 0);
    phase_bar();
    MFMA_Q(0);
    phase_bar();

    // ---- phase 2: A quadrant 1; stage A-half1(t+1)
    READ_A(1);
    if (t < 11) STAGE_A(buf ^ 1, ktn, 1);
    phase_bar();
    MFMA_Q(1);
    phase_bar();

    // ---- phase 3: A quadrant 2; stage B-half1(t+1)
    READ_A(2);
    if (t < 11) STAGE_B(buf ^ 1, ktn, 1);
    phase_bar();
    MFMA_Q(2);
    phase_bar();

    // ---- phase 4: A quadrant 3; stage B-half0(t+2); counted vmcnt
    READ_A(3);
    if (t < 10) STAGE_B(buf, ktn + 64, 0);
    phase_bar();
    MFMA_Q(3);
    if (t < 10) { asm volatile("s_waitcnt vmcnt(2)" ::: "memory"); }
    else        { asm volatile("s_waitcnt vmcnt(0)" ::: "memory"); }
    phase_bar();
  }

  if (EPI == 0) {
#pragma unroll
    for (int ni = 0; ni < 4; ni++) {
      const int n = n0 + wn + ni * 16 + l16;
      const int which = n / 768;          // constant per ni-block (64 | 768)
      const int rc = n % 768;
      const int head = rc >> 6, d = rc & 63;
#pragma unroll
      for (int mi = 0; mi < 8; mi++) {
#pragma unroll
        for (int r = 0; r < 4; r++) {
          const int m = m0 + wm + mi * 16 + quad * 4 + r;
          const int b = m >> 10, rr = m & 1023;
          const float val = acc[mi][ni][r];
          if (which == 0)   // fold SCALE * log2(e) so flash uses 2^x directly
            q[((size_t)(b * NHEAD + head) * SEQ + rr) * HD + d] = f2bf(val * 0.18033688011112042f);
          else if (which == 1)
            k[((size_t)(b * NHEAD + head) * SEQ + rr) * HD + d] = f2bf(val);
          else
            v[((size_t)(b * NHEAD + head) * HD + d) * SEQ + rr] = f2bf(val);
        }
      }
    }
  } else {
#pragma unroll
    for (int mi = 0; mi < 8; mi++)
#pragma unroll
      for (int ni = 0; ni < 4; ni++)
#pragma unroll
        for (int r = 0; r < 4; r++) {
          const int m = m0 + wm + mi * 16 + quad * 4 + r;
          const int n = n0 + wn + ni * 16 + l16;
          out[(size_t)m * 768 + n] = acc[mi][ni][r] + bias[n];
        }
  }
#undef STAGE_A
#undef STAGE_B
#undef READ_A
#undef READ_B
#undef MFMA_Q
}

// Flash attention, S^T form, no online max, 2^x, double-buffered K/V staging.
// l computed as P @ ones via MFMA (acc_l lands in same C-layout rows as acc).
__global__ __launch_bounds__(256, 3)
void flash_attn(const u16* __restrict__ Q, const u16* __restrict__ K,
                const u16* __restrict__ VT, u16* __restrict__ O) {
  __shared__ u16 Ks[2][64 * 64];        // [key][d], chunks swizzled by key&7
  __shared__ u16 Vs[2][64 * 64];        // [d][key], chunks swizzled by d&7
  __shared__ u16 Ps[4][32 * 64];        // per-wave [qrow][key]

  const int tid = threadIdx.x;
  const int wv = tid >> 6, lane = tid & 63;
  const int quad = lane >> 4, l16 = lane & 15;
  const int bh = blockIdx.x;
  const int q0 = blockIdx.y * 128 + wv * 32;
  const size_t base = (size_t)bh * SEQ * HD;
  const size_t vbase = (size_t)bh * HD * SEQ;
  u16* pw = Ps[wv];

  const int sr0 = tid >> 3;
  const int sc0 = (tid & 7) ^ (sr0 & 7);
  const int sr1 = 32 + sr0;
  const int sc1 = (tid & 7) ^ (sr1 & 7);

  s16x8 qf[2][2];
#pragma unroll
  for (int g = 0; g < 2; g++)
#pragma unroll
    for (int ks = 0; ks < 2; ks++)
      qf[g][ks] = *(const s16x8*)(Q + base + (size_t)(q0 + g * 16 + l16) * HD + ks * 32 + quad * 8);

  const s16x8 ones = {0x3F80, 0x3F80, 0x3F80, 0x3F80, 0x3F80, 0x3F80, 0x3F80, 0x3F80};

  f32x4 acc[2][4], acc_l[2];
#pragma unroll
  for (int g = 0; g < 2; g++) {
    acc_l[g].x = 0.f; acc_l[g].y = 0.f; acc_l[g].z = 0.f; acc_l[g].w = 0.f;
#pragma unroll
    for (int t = 0; t < 4; t++) { acc[g][t].x = 0.f; acc[g][t].y = 0.f; acc[g][t].z = 0.f; acc[g][t].w = 0.f; }
  }

  const int swz = l16 & 7;

  gld_lds16(K + base + (size_t)sr0 * HD + sc0 * 8, &Ks[0][wv * 512]);
  gld_lds16(VT + vbase + (size_t)sr0 * SEQ + sc0 * 8, &Vs[0][wv * 512]);
  gld_lds16(K + base + (size_t)sr1 * HD + sc1 * 8, &Ks[0][2048 + wv * 512]);
  gld_lds16(VT + vbase + (size_t)sr1 * SEQ + sc1 * 8, &Vs[0][2048 + wv * 512]);

  for (int it = 0; it < 16; it++) {
    __syncthreads();
    if (it + 1 < 16) {
      const int n1 = (it + 1) * 64;
      const int nb = (it + 1) & 1;
      gld_lds16(K + base + (size_t)(n1 + sr0) * HD + sc0 * 8, &Ks[nb][wv * 512]);
      gld_lds16(VT + vbase + (size_t)sr0 * SEQ + n1 + sc0 * 8, &Vs[nb][wv * 512]);
      gld_lds16(K + base + (size_t)(n1 + sr1) * HD + sc1 * 8, &Ks[nb][2048 + wv * 512]);
      gld_lds16(VT + vbase + (size_t)sr1 * SEQ + n1 + sc1 * 8, &Vs[nb][2048 + wv * 512]);
    }
    const u16* __restrict__ ks = Ks[it & 1];
    const u16* __restrict__ vs = Vs[it & 1];

    // S^T = K Q^T (q pre-scaled by 0.125*log2e)
    f32x4 s0[4], s1[4];
#pragma unroll
    for (int t = 0; t < 4; t++) {
      s0[t].x = 0.f; s0[t].y = 0.f; s0[t].z = 0.f; s0[t].w = 0.f;
      s1[t].x = 0.f; s1[t].y = 0.f; s1[t].z = 0.f; s1[t].w = 0.f;
      const u16* kr = &ks[(t * 16 + l16) * 64];
      const s16x8 kf0 = *(const s16x8*)&kr[(quad ^ swz) * 8];
      const s16x8 kf1 = *(const s16x8*)&kr[((4 + quad) ^ swz) * 8];
      s0[t] = __builtin_amdgcn_mfma_f32_16x16x32_bf16(kf0, qf[0][0], s0[t], 0, 0, 0);
      s0[t] = __builtin_amdgcn_mfma_f32_16x16x32_bf16(kf1, qf[0][1], s0[t], 0, 0, 0);
      s1[t] = __builtin_amdgcn_mfma_f32_16x16x32_bf16(kf0, qf[1][0], s1[t], 0, 0, 0);
      s1[t] = __builtin_amdgcn_mfma_f32_16x16x32_bf16(kf1, qf[1][1], s1[t], 0, 0, 0);
    }

    // p = 2^s
#pragma unroll
    for (int t = 0; t < 4; t++)
#pragma unroll
      for (int r = 0; r < 4; r++) {
        s0[t][r] = exp2_fast(s0[t][r]);
        s1[t][r] = exp2_fast(s1[t][r]);
      }

    // P -> per-wave LDS, packed b64, chunk-swizzled
#pragma unroll
    for (int t = 0; t < 4; t++) {
      const int p = (2 * t + (quad >> 1)) ^ swz;
      *(uint2*)&pw[l16 * 64 + p * 8 + (quad & 1) * 4] =
          make_uint2(pk_bf16(s0[t][0], s0[t][1]), pk_bf16(s0[t][2], s0[t][3]));
      *(uint2*)&pw[(16 + l16) * 64 + p * 8 + (quad & 1) * 4] =
          make_uint2(pk_bf16(s1[t][0], s1[t][1]), pk_bf16(s1[t][2], s1[t][3]));
    }

    // O += P V ; l += P @ ones (matrix pipe does the row sums)
#pragma unroll
    for (int ks2 = 0; ks2 < 2; ks2++) {
      const int cp = ((ks2 * 4 + quad) ^ swz) * 8;
      const s16x8 pf0 = *(const s16x8*)&pw[l16 * 64 + cp];
      const s16x8 pf1 = *(const s16x8*)&pw[(16 + l16) * 64 + cp];
      acc_l[0] = __builtin_amdgcn_mfma_f32_16x16x32_bf16(pf0, ones, acc_l[0], 0, 0, 0);
      acc_l[1] = __builtin_amdgcn_mfma_f32_16x16x32_bf16(pf1, ones, acc_l[1], 0, 0, 0);
#pragma unroll
      for (int t2 = 0; t2 < 4; t2++) {
        const s16x8 vf = *(const s16x8*)&vs[(t2 * 16 + l16) * 64 + cp];
        acc[0][t2] = __builtin_amdgcn_mfma_f32_16x16x32_bf16(pf0, vf, acc[0][t2], 0, 0, 0);
        acc[1][t2] = __builtin_amdgcn_mfma_f32_16x16x32_bf16(pf1, vf, acc[1][t2], 0, 0, 0);
      }
    }
  }

  // write attn_out bf16 [B, N, H*64]; acc_l rows coincide with acc rows
  const int b = bh / NHEAD, h = bh % NHEAD;
#pragma unroll
  for (int g = 0; g < 2; g++) {
#pragma unroll
    for (int r = 0; r < 4; r++) {
      const float li = 1.0f / acc_l[g][r];
      const int qrow = q0 + g * 16 + quad * 4 + r;
      u16* op = O + (size_t)(b * SEQ + qrow) * 768 + h * HD;
#pragma unroll
      for (int t2 = 0; t2 < 4; t2++)
        op[t2 * 16 + l16] = f2bf(acc[g][t2][r] * li);
    }
  }
}

extern "C" void kernel_launch(void* const* d_in, const int* in_sizes, int n_in,
                              void* d_out, int out_size, void* d_ws, size_t ws_size,
                              hipStream_t stream) {
  (void)in_sizes; (void)n_in; (void)out_size; (void)ws_size;
  const float* x      = (const float*)d_in[0];
  const float* w_qkv  = (const float*)d_in[1];
  const float* w_proj = (const float*)d_in[2];
  const float* b_proj = (const float*)d_in[3];

  const size_t SZ_X   = (size_t)16384 * 768;
  const size_t SZ_WQ  = (size_t)2304 * 768;
  const size_t SZ_WP  = (size_t)768 * 768;
  const size_t SZ_HED = (size_t)16 * NHEAD * SEQ * HD;

  u16* xb   = (u16*)d_ws;
  u16* wqb  = xb + SZ_X;
  u16* wpb  = wqb + SZ_WQ;
  u16* qb   = wpb + SZ_WP;
  u16* kb   = qb + SZ_HED;
  u16* vtb  = kb + SZ_HED;     // V transposed [bh][d][n]
  u16* attn = vtb + SZ_HED;

  cvt_bf16<<<(int)(SZ_X / 4 / 256), 256, 0, stream>>>(x, xb, (int)(SZ_X / 4));
  cvt_bf16<<<(int)(SZ_WQ / 4 / 256), 256, 0, stream>>>(w_qkv, wqb, (int)(SZ_WQ / 4));
  cvt_bf16<<<(int)(SZ_WP / 4 / 256), 256, 0, stream>>>(w_proj, wpb, (int)(SZ_WP / 4));

  gemm_bt<0><<<dim3(576), 512, 0, stream>>>(xb, wqb, qb, kb, vtb, nullptr, nullptr);
  flash_attn<<<dim3(192, 8), 256, 0, stream>>>(qb, kb, vtb, attn);
  gemm_bt<1><<<dim3(192), 512, 0, stream>>>(attn, wpb, nullptr, nullptr, nullptr,
                                            (float*)d_out, b_proj);
}